// Round 23
// baseline (115.531 us; speedup 1.0000x reference)
//
#include <hip/hip_runtime.h>
#include <math.h>

namespace {
constexpr int B = 4, R = 10, N = 64, E = 64, D = 300, H = 512;
constexpr int BR = B * R;        // 40
constexpr int NE = N * E;        // 4096
constexpr int S = BR * NE;       // 163840
constexpr float SLOPE = 0.2f;
constexpr int WO_BLOCKS = BR * 8;        // 320
constexpr int S2_ROWS = 32;              // rows per block (8 lanes/row, 256 thr)
constexpr int S2_BLOCKS = S / S2_ROWS;   // 5120

// ws layout (floats)
constexpr int OFF_V1  = 0;                 // 300   Wn @ a1
constexpr int OFF_V2  = OFF_V1 + 300;      // 300   Wn @ a2
constexpr int OFF_U1  = OFF_V2 + 300;      // 512   Wq @ a1
constexpr int OFF_U2  = OFF_U1 + H;        // 512   Wq @ a2
constexpr int OFF_QP  = OFF_U2 + H;        // 40*512 q_proj
constexpr int OFF_QA1 = OFF_QP + BR * H;   // 40
constexpr int OFF_QA2 = OFF_QA1 + BR;      // 40
constexpr int OFF_S1  = OFF_QA2 + BR;      // 2560  scores1[b,r,n] (incl. qa1)
constexpr int OFF_RAW = OFF_S1 + BR * N;   // 163840 raw adj.v2 dots (pre-leaky)
constexpr int OFF_SC  = OFF_RAW + S;       // 163840 attn (post-softmax)
constexpr int OFF_WO  = OFF_SC + S;        // 1310720 w_original
}

__device__ inline float waveReduce(float v) {
#pragma unroll
  for (int o = 32; o > 0; o >>= 1) v += __shfl_xor(v, o, 64);
  return v;
}

__device__ inline float dot4(float4 a, float4 b) {
  return a.x * b.x + a.y * b.y + a.z * b.z + a.w * b.w;
}

// grid 812 x 64: one wave per W row; dot with a1 and a2.
__global__ __launch_bounds__(64) void k_vecs(const float* __restrict__ W,
                                             const float* __restrict__ a,
                                             float* __restrict__ ws) {
  int row = blockIdx.x;
  int lane = threadIdx.x;
  const float4* rf  = reinterpret_cast<const float4*>(W + (size_t)row * H);
  const float4* a1f = reinterpret_cast<const float4*>(a);
  const float4* a2f = reinterpret_cast<const float4*>(a + H);
  float4 x0 = rf[lane], x1 = rf[64 + lane];
  float4 p0 = a1f[lane], p1 = a1f[64 + lane];
  float4 q0 = a2f[lane], q1 = a2f[64 + lane];
  float s1 = dot4(x0, p0) + dot4(x1, p1);
  float s2 = dot4(x0, q0) + dot4(x1, q1);
  s1 = waveReduce(s1);
  s2 = waveReduce(s2);
  if (lane == 0) {
    if (row < D) { ws[OFF_V1 + row] = s1; ws[OFF_V2 + row] = s2; }
    else         { ws[OFF_U1 + (row - D)] = s1; ws[OFF_U2 + (row - D)] = s2; }
  }
}

// grid 40 x 512: q_proj (4-way ILP accumulators) + qa1/qa2 + scores1 (2-row batch).
__global__ __launch_bounds__(512) void k_qproj_s1(const float* __restrict__ ques,
                                                  const float* __restrict__ W,
                                                  const float* __restrict__ orig,
                                                  float* __restrict__ ws) {
  int br = blockIdx.x, h = threadIdx.x;
  __shared__ float qs[H];
  __shared__ float red[16];
  __shared__ float qa1s;
  qs[h] = ques[(size_t)br * H + h];
  __syncthreads();
  float ac0 = 0.f, ac1 = 0.f, ac2 = 0.f, ac3 = 0.f;
#pragma unroll 4
  for (int q = 0; q < H; q += 4) {
    ac0 = fmaf(qs[q + 0], W[(size_t)(D + q + 0) * H + h], ac0);
    ac1 = fmaf(qs[q + 1], W[(size_t)(D + q + 1) * H + h], ac1);
    ac2 = fmaf(qs[q + 2], W[(size_t)(D + q + 2) * H + h], ac2);
    ac3 = fmaf(qs[q + 3], W[(size_t)(D + q + 3) * H + h], ac3);
  }
  float acc = (ac0 + ac1) + (ac2 + ac3);
  ws[OFF_QP + br * H + h] = acc;
  float p1 = qs[h] * ws[OFF_U1 + h];
  float p2 = qs[h] * ws[OFF_U2 + h];
  p1 = waveReduce(p1);
  p2 = waveReduce(p2);
  int lane = h & 63, wave = h >> 6;
  if (lane == 0) { red[wave] = p1; red[8 + wave] = p2; }
  __syncthreads();
  if (h == 0) {
    float t1 = 0.f, t2 = 0.f;
#pragma unroll
    for (int i = 0; i < 8; ++i) { t1 += red[i]; t2 += red[8 + i]; }
    ws[OFF_QA1 + br] = t1;
    ws[OFF_QA2 + br] = t2;
    qa1s = t1;
  }
  __syncthreads();
  float qa1 = qa1s;
  const float4* vf = reinterpret_cast<const float4*>(ws + OFF_V1);
  float4 va = vf[lane];
  float4 vb = (lane < 11) ? vf[64 + lane] : make_float4(0.f, 0.f, 0.f, 0.f);
  for (int n2 = wave * 8; n2 < wave * 8 + 8; n2 += 2) {
    const float4* rf0 = reinterpret_cast<const float4*>(orig + ((size_t)br * N + n2) * D);
    const float4* rf1 = reinterpret_cast<const float4*>(orig + ((size_t)br * N + n2 + 1) * D);
    float a0 = dot4(rf0[lane], va);
    float a1 = dot4(rf1[lane], va);
    if (lane < 11) {
      a0 += dot4(rf0[64 + lane], vb);
      a1 += dot4(rf1[64 + lane], vb);
    }
#pragma unroll
    for (int o = 32; o > 0; o >>= 1) {
      a0 += __shfl_xor(a0, o, 64);
      a1 += __shfl_xor(a1, o, 64);
    }
    if (lane == 0) {
      ws[OFF_S1 + br * N + n2]     = a0 + qa1;
      ws[OFF_S1 + br * N + n2 + 1] = a1 + qa1;
    }
  }
}

// grid 5440 x 256, block-split:
//   blocks 0..319:    wo GEMM (br, h0), BK=30 (15360B LDS, R18/R22-verified).
//   blocks 320..5439: s2 — 8 lanes/row, 10 EXPLICITLY-NAMED float4 loads per
//                     thread (no loop: forces the compiler to issue all 10
//                     before the first consuming FMA -> 9+ loads in flight
//                     per wave under descending vmcnt waits). v2 from LDS
//                     (lgkmcnt, doesn't stall vmem). 3-step shfl reduce.
//                     Target ~90 VGPR -> ~20 waves/CU -> ~200KB/CU in flight.
__global__ __launch_bounds__(256) void k_s2wo(const float* __restrict__ adj,
                                              const float* __restrict__ orig,
                                              const float* __restrict__ W,
                                              float* __restrict__ ws) {
  __shared__ __align__(16) float smem[64 * 30 + 30 * 64];   // 15360 B
  int t = threadIdx.x;
  if (blockIdx.x < WO_BLOCKS) {
    // ---- w_original tile GEMM, BK=30 (verified branch, verbatim) ----
    int bi = blockIdx.x;
    int br = bi >> 3, h0 = (bi & 7) * 64;
    float* sA = smem;             // 64 x 30
    float* sB = smem + 1920;      // 30 x 64
    const float4* sBf = reinterpret_cast<const float4*>(sB);
    int tn = t >> 4, th = t & 15;
    float acc[4][4] = {};
    for (int k0 = 0; k0 < D; k0 += 30) {
      __syncthreads();
      for (int idx = t; idx < 64 * 30; idx += 256) {
        int n = idx / 30, kk = idx % 30;
        sA[idx] = orig[((size_t)br * N + n) * D + k0 + kk];
      }
      for (int idx = t; idx < 30 * 64; idx += 256) {
        int kk = idx >> 6, hh = idx & 63;
        sB[idx] = W[(size_t)(k0 + kk) * H + h0 + hh];
      }
      __syncthreads();
#pragma unroll 5
      for (int kk = 0; kk < 30; ++kk) {
        float av[4];
#pragma unroll
        for (int i = 0; i < 4; ++i) av[i] = sA[(tn * 4 + i) * 30 + kk];
        float4 bv = sBf[kk * 16 + th];
#pragma unroll
        for (int i = 0; i < 4; ++i) {
          acc[i][0] = fmaf(av[i], bv.x, acc[i][0]);
          acc[i][1] = fmaf(av[i], bv.y, acc[i][1]);
          acc[i][2] = fmaf(av[i], bv.z, acc[i][2]);
          acc[i][3] = fmaf(av[i], bv.w, acc[i][3]);
        }
      }
    }
#pragma unroll
    for (int i = 0; i < 4; ++i) {
      int n = tn * 4 + i;
#pragma unroll
      for (int j = 0; j < 4; ++j) {
        int h = h0 + th * 4 + j;
        ws[OFF_WO + ((size_t)br * N + n) * H + h] = acc[i][j] + ws[OFF_QP + br * H + h];
      }
    }
    return;
  }
  // ---- s2: named-register streaming dot ----
  for (int i = t; i < 300; i += 256) smem[i] = ws[OFF_V2 + i];
  __syncthreads();
  const float4* v4 = reinterpret_cast<const float4*>(smem);
  int row = (blockIdx.x - WO_BLOCKS) * S2_ROWS + (t >> 3);
  int g = t & 7;
  const float4* ap = reinterpret_cast<const float4*>(adj) + (size_t)row * 75;
  // 9 unconditional loads (g+64 <= 71 < 75) + 1 guarded (g+72, valid g<3).
  float4 L0 = ap[g +  0], L1 = ap[g +  8], L2 = ap[g + 16];
  float4 L3 = ap[g + 24], L4 = ap[g + 32], L5 = ap[g + 40];
  float4 L6 = ap[g + 48], L7 = ap[g + 56], L8 = ap[g + 64];
  float4 L9 = make_float4(0.f, 0.f, 0.f, 0.f);
  float4 V9 = L9;
  if (g < 3) { L9 = ap[g + 72]; V9 = v4[g + 72]; }
  float4 V0 = v4[g +  0], V1 = v4[g +  8], V2 = v4[g + 16];
  float4 V3 = v4[g + 24], V4 = v4[g + 32], V5 = v4[g + 40];
  float4 V6 = v4[g + 48], V7 = v4[g + 56], V8 = v4[g + 64];
  float a0 = dot4(L0, V0) + dot4(L2, V2) + dot4(L4, V4) + dot4(L6, V6) + dot4(L8, V8);
  float a1 = dot4(L1, V1) + dot4(L3, V3) + dot4(L5, V5) + dot4(L7, V7) + dot4(L9, V9);
  float acc = a0 + a1;
  acc += __shfl_xor(acc, 1, 64);
  acc += __shfl_xor(acc, 2, 64);
  acc += __shfl_xor(acc, 4, 64);
  if (g == 0) ws[OFF_RAW + row] = acc;
}

// grid 64 x 256: per (b,n,e): add s1+qa2, leaky, softmax over r, write attn.
__global__ __launch_bounds__(256) void k_softmax(float* __restrict__ ws) {
  int t = blockIdx.x * 256 + threadIdx.x;  // 0..16383 = B*N*E
  int b = t >> 12;
  int ne = t & 4095;
  int n = ne >> 6;
  const float* raw = ws + OFF_RAW;
  float v[R];
  float m = -1e30f;
#pragma unroll
  for (int r = 0; r < R; ++r) {
    int br = b * R + r;
    float sc = raw[(size_t)br * NE + ne] + ws[OFF_QA2 + br] + ws[OFF_S1 + br * N + n];
    sc = sc > 0.f ? sc : SLOPE * sc;
    v[r] = sc;
    m = fmaxf(m, sc);
  }
  float s = 0.f;
#pragma unroll
  for (int r = 0; r < R; ++r) { v[r] = __expf(v[r] - m); s += v[r]; }
  float inv = 1.f / s;
#pragma unroll
  for (int r = 0; r < R; ++r)
    ws[OFF_SC + (size_t)(b * R + r) * NE + ne] = v[r] * inv;
}

// grid (40, 8) x 256: h_prime[br] = attn[br] @ w_original[br], then ELU.
__global__ __launch_bounds__(256) void k_hprime(const float* __restrict__ ws,
                                                float* __restrict__ out) {
  int br = blockIdx.x;
  int h = blockIdx.y * 64 + (threadIdx.x & 63);
  int ig = threadIdx.x >> 6;   // 0..3 -> rows ig*16..ig*16+15
  __shared__ __align__(16) float sAtt[64 * 64];
  const float* att = ws + OFF_SC + (size_t)br * NE;
  for (int idx = threadIdx.x; idx < 4096; idx += 256) sAtt[idx] = att[idx];
  __syncthreads();
  float acc[16] = {};
  const float* wo = ws + OFF_WO + (size_t)br * N * H;
  const float4* sAttf = reinterpret_cast<const float4*>(sAtt);
#pragma unroll 2
  for (int j4 = 0; j4 < 16; ++j4) {
    float w0 = wo[(size_t)(4 * j4 + 0) * H + h];
    float w1 = wo[(size_t)(4 * j4 + 1) * H + h];
    float w2 = wo[(size_t)(4 * j4 + 2) * H + h];
    float w3 = wo[(size_t)(4 * j4 + 3) * H + h];
#pragma unroll
    for (int ii = 0; ii < 16; ++ii) {
      float4 a4 = sAttf[(ig * 16 + ii) * 16 + j4];
      acc[ii] = fmaf(a4.x, w0, fmaf(a4.y, w1, fmaf(a4.z, w2, fmaf(a4.w, w3, acc[ii]))));
    }
  }
#pragma unroll
  for (int ii = 0; ii < 16; ++ii) {
    int i = ig * 16 + ii;
    float x = acc[ii];
    out[((size_t)br * N + i) * H + h] = x > 0.f ? x : expm1f(x);
  }
}

extern "C" void kernel_launch(void* const* d_in, const int* in_sizes, int n_in,
                              void* d_out, int out_size, void* d_ws, size_t ws_size,
                              hipStream_t stream) {
  const float* adj  = (const float*)d_in[0];
  const float* orig = (const float*)d_in[1];
  const float* ques = (const float*)d_in[2];
  const float* W    = (const float*)d_in[3];
  const float* a    = (const float*)d_in[4];
  float* out = (float*)d_out;
  float* ws  = (float*)d_ws;

  k_vecs<<<dim3(D + H), dim3(64), 0, stream>>>(W, a, ws);
  k_qproj_s1<<<dim3(BR), dim3(512), 0, stream>>>(ques, W, orig, ws);
  k_s2wo<<<dim3(WO_BLOCKS + S2_BLOCKS), dim3(256), 0, stream>>>(adj, orig, W, ws);
  k_softmax<<<dim3(B * NE / 256), dim3(256), 0, stream>>>(ws);
  k_hprime<<<dim3(BR, 8), dim3(256), 0, stream>>>(ws, out);
}

// Round 24
// 113.354 us; speedup vs baseline: 1.0192x; 1.0192x over previous
//
#include <hip/hip_runtime.h>
#include <math.h>

namespace {
constexpr int B = 4, R = 10, N = 64, E = 64, D = 300, H = 512;
constexpr int BR = B * R;        // 40
constexpr int NE = N * E;        // 4096
constexpr int S = BR * NE;       // 163840
constexpr float SLOPE = 0.2f;
constexpr int WO_BLOCKS = BR * 8;        // 320
constexpr int S2_ROWS = 32;              // rows per block (38.4KB contiguous slab)
constexpr int S2_BLOCKS = S / S2_ROWS;   // 5120
constexpr int SLAB_F4 = S2_ROWS * 75;    // 2400 float4s per slab

// ws layout (floats)
constexpr int OFF_V1  = 0;                 // 300   Wn @ a1
constexpr int OFF_V2  = OFF_V1 + 300;      // 300   Wn @ a2
constexpr int OFF_U1  = OFF_V2 + 300;      // 512   Wq @ a1
constexpr int OFF_U2  = OFF_U1 + H;        // 512   Wq @ a2
constexpr int OFF_QP  = OFF_U2 + H;        // 40*512 q_proj
constexpr int OFF_QA1 = OFF_QP + BR * H;   // 40
constexpr int OFF_QA2 = OFF_QA1 + BR;      // 40
constexpr int OFF_S1  = OFF_QA2 + BR;      // 2560  scores1[b,r,n] (incl. qa1)
constexpr int OFF_RAW = OFF_S1 + BR * N;   // 163840 raw adj.v2 dots (pre-leaky)
constexpr int OFF_SC  = OFF_RAW + S;       // 163840 attn (post-softmax)
constexpr int OFF_WO  = OFF_SC + S;        // 1310720 w_original
}

__device__ inline float waveReduce(float v) {
#pragma unroll
  for (int o = 32; o > 0; o >>= 1) v += __shfl_xor(v, o, 64);
  return v;
}

__device__ inline float dot4(float4 a, float4 b) {
  return a.x * b.x + a.y * b.y + a.z * b.z + a.w * b.w;
}

// grid 812 x 64: one wave per W row; dot with a1 and a2.
__global__ __launch_bounds__(64) void k_vecs(const float* __restrict__ W,
                                             const float* __restrict__ a,
                                             float* __restrict__ ws) {
  int row = blockIdx.x;
  int lane = threadIdx.x;
  const float4* rf  = reinterpret_cast<const float4*>(W + (size_t)row * H);
  const float4* a1f = reinterpret_cast<const float4*>(a);
  const float4* a2f = reinterpret_cast<const float4*>(a + H);
  float4 x0 = rf[lane], x1 = rf[64 + lane];
  float4 p0 = a1f[lane], p1 = a1f[64 + lane];
  float4 q0 = a2f[lane], q1 = a2f[64 + lane];
  float s1 = dot4(x0, p0) + dot4(x1, p1);
  float s2 = dot4(x0, q0) + dot4(x1, q1);
  s1 = waveReduce(s1);
  s2 = waveReduce(s2);
  if (lane == 0) {
    if (row < D) { ws[OFF_V1 + row] = s1; ws[OFF_V2 + row] = s2; }
    else         { ws[OFF_U1 + (row - D)] = s1; ws[OFF_U2 + (row - D)] = s2; }
  }
}

// grid 40 x 512: q_proj (4-way ILP accumulators) + qa1/qa2 + scores1 (2-row batch).
__global__ __launch_bounds__(512) void k_qproj_s1(const float* __restrict__ ques,
                                                  const float* __restrict__ W,
                                                  const float* __restrict__ orig,
                                                  float* __restrict__ ws) {
  int br = blockIdx.x, h = threadIdx.x;
  __shared__ float qs[H];
  __shared__ float red[16];
  __shared__ float qa1s;
  qs[h] = ques[(size_t)br * H + h];
  __syncthreads();
  float ac0 = 0.f, ac1 = 0.f, ac2 = 0.f, ac3 = 0.f;
#pragma unroll 4
  for (int q = 0; q < H; q += 4) {
    ac0 = fmaf(qs[q + 0], W[(size_t)(D + q + 0) * H + h], ac0);
    ac1 = fmaf(qs[q + 1], W[(size_t)(D + q + 1) * H + h], ac1);
    ac2 = fmaf(qs[q + 2], W[(size_t)(D + q + 2) * H + h], ac2);
    ac3 = fmaf(qs[q + 3], W[(size_t)(D + q + 3) * H + h], ac3);
  }
  float acc = (ac0 + ac1) + (ac2 + ac3);
  ws[OFF_QP + br * H + h] = acc;
  float p1 = qs[h] * ws[OFF_U1 + h];
  float p2 = qs[h] * ws[OFF_U2 + h];
  p1 = waveReduce(p1);
  p2 = waveReduce(p2);
  int lane = h & 63, wave = h >> 6;
  if (lane == 0) { red[wave] = p1; red[8 + wave] = p2; }
  __syncthreads();
  if (h == 0) {
    float t1 = 0.f, t2 = 0.f;
#pragma unroll
    for (int i = 0; i < 8; ++i) { t1 += red[i]; t2 += red[8 + i]; }
    ws[OFF_QA1 + br] = t1;
    ws[OFF_QA2 + br] = t2;
    qa1s = t1;
  }
  __syncthreads();
  float qa1 = qa1s;
  const float4* vf = reinterpret_cast<const float4*>(ws + OFF_V1);
  float4 va = vf[lane];
  float4 vb = (lane < 11) ? vf[64 + lane] : make_float4(0.f, 0.f, 0.f, 0.f);
  for (int n2 = wave * 8; n2 < wave * 8 + 8; n2 += 2) {
    const float4* rf0 = reinterpret_cast<const float4*>(orig + ((size_t)br * N + n2) * D);
    const float4* rf1 = reinterpret_cast<const float4*>(orig + ((size_t)br * N + n2 + 1) * D);
    float a0 = dot4(rf0[lane], va);
    float a1 = dot4(rf1[lane], va);
    if (lane < 11) {
      a0 += dot4(rf0[64 + lane], vb);
      a1 += dot4(rf1[64 + lane], vb);
    }
#pragma unroll
    for (int o = 32; o > 0; o >>= 1) {
      a0 += __shfl_xor(a0, o, 64);
      a1 += __shfl_xor(a1, o, 64);
    }
    if (lane == 0) {
      ws[OFF_S1 + br * N + n2]     = a0 + qa1;
      ws[OFF_S1 + br * N + n2 + 1] = a1 + qa1;
    }
  }
}

// grid 5440 x 256, block-split:
//   blocks 0..319:    wo GEMM (br, h0), BK=30 (verified branch).
//   blocks 320..5439: s2 — slab staged via ASYNC global_load_lds (width=16):
//                     outstanding loads live in the vmcnt queue with LDS as
//                     sink, ZERO destination VGPRs -> in-flight bytes no
//                     longer capped by registers (the failure mode of R17/
//                     R22/R23). ~4 blocks/CU x 38.4KB = 150KB/CU in flight.
//                     LDS stays LINEAR (wave-uniform base + lane*16; no pad).
__global__ __launch_bounds__(256) void k_s2wo(const float* __restrict__ adj,
                                              const float* __restrict__ orig,
                                              const float* __restrict__ W,
                                              float* __restrict__ ws) {
  __shared__ __align__(16) float4 slab[SLAB_F4];   // 38400 B
  __shared__ float v2s[300];                       // 1200 B
  int t = threadIdx.x;
  if (blockIdx.x < WO_BLOCKS) {
    // ---- w_original tile GEMM, BK=30 (verified branch, verbatim) ----
    float* smem = reinterpret_cast<float*>(slab);
    int bi = blockIdx.x;
    int br = bi >> 3, h0 = (bi & 7) * 64;
    float* sA = smem;             // 64 x 30
    float* sB = smem + 1920;      // 30 x 64
    const float4* sBf = reinterpret_cast<const float4*>(sB);
    int tn = t >> 4, th = t & 15;
    float acc[4][4] = {};
    for (int k0 = 0; k0 < D; k0 += 30) {
      __syncthreads();
      for (int idx = t; idx < 64 * 30; idx += 256) {
        int n = idx / 30, kk = idx % 30;
        sA[idx] = orig[((size_t)br * N + n) * D + k0 + kk];
      }
      for (int idx = t; idx < 30 * 64; idx += 256) {
        int kk = idx >> 6, hh = idx & 63;
        sB[idx] = W[(size_t)(k0 + kk) * H + h0 + hh];
      }
      __syncthreads();
#pragma unroll 5
      for (int kk = 0; kk < 30; ++kk) {
        float av[4];
#pragma unroll
        for (int i = 0; i < 4; ++i) av[i] = sA[(tn * 4 + i) * 30 + kk];
        float4 bv = sBf[kk * 16 + th];
#pragma unroll
        for (int i = 0; i < 4; ++i) {
          acc[i][0] = fmaf(av[i], bv.x, acc[i][0]);
          acc[i][1] = fmaf(av[i], bv.y, acc[i][1]);
          acc[i][2] = fmaf(av[i], bv.z, acc[i][2]);
          acc[i][3] = fmaf(av[i], bv.w, acc[i][3]);
        }
      }
    }
#pragma unroll
    for (int i = 0; i < 4; ++i) {
      int n = tn * 4 + i;
#pragma unroll
      for (int j = 0; j < 4; ++j) {
        int h = h0 + th * 4 + j;
        ws[OFF_WO + ((size_t)br * N + n) * H + h] = acc[i][j] + ws[OFF_QP + br * H + h];
      }
    }
    return;
  }
  // ---- s2: async slab staging via global_load_lds ----
  int sb = blockIdx.x - WO_BLOCKS;
  const float4* src = reinterpret_cast<const float4*>(adj) + (size_t)sb * SLAB_F4;
  int wbase = t & ~63;   // wave-uniform float4 base within each 256-chunk
  // 9 full iterations: all 256 threads; lds dest = wave-uniform base (+lane*16 in HW).
#pragma unroll
  for (int j = 0; j < 9; ++j) {
    __builtin_amdgcn_global_load_lds(
        (const __attribute__((address_space(1))) void*)(src + j * 256 + t),
        (__attribute__((address_space(3))) void*)(slab + j * 256 + wbase),
        16, 0, 0);
  }
  // tail: 2400 - 2304 = 96 float4s (threads 0..95)
  if (t < 96) {
    __builtin_amdgcn_global_load_lds(
        (const __attribute__((address_space(1))) void*)(src + 2304 + t),
        (__attribute__((address_space(3))) void*)(slab + 2304 + wbase),
        16, 0, 0);
  }
  // v2 into LDS (regular loads; drained by the same pre-barrier waitcnt).
  for (int i = t; i < 300; i += 256) v2s[i] = ws[OFF_V2 + i];
  __syncthreads();
  const float4* v4 = reinterpret_cast<const float4*>(v2s);
  int row = t >> 3, g = t & 7;
  float acc = 0.f;
#pragma unroll
  for (int k = 0; k < 10; ++k) {
    int j = g + 8 * k;
    if (j < 75) {
      float4 x = slab[row * 75 + j];
      float4 v = v4[j];
      acc = fmaf(x.x, v.x, fmaf(x.y, v.y, fmaf(x.z, v.z, fmaf(x.w, v.w, acc))));
    }
  }
  acc += __shfl_xor(acc, 1, 64);
  acc += __shfl_xor(acc, 2, 64);
  acc += __shfl_xor(acc, 4, 64);
  if (g == 0) ws[OFF_RAW + (size_t)sb * S2_ROWS + row] = acc;
}

// grid 64 x 256: per (b,n,e): add s1+qa2, leaky, softmax over r, write attn.
__global__ __launch_bounds__(256) void k_softmax(float* __restrict__ ws) {
  int t = blockIdx.x * 256 + threadIdx.x;  // 0..16383 = B*N*E
  int b = t >> 12;
  int ne = t & 4095;
  int n = ne >> 6;
  const float* raw = ws + OFF_RAW;
  float v[R];
  float m = -1e30f;
#pragma unroll
  for (int r = 0; r < R; ++r) {
    int br = b * R + r;
    float sc = raw[(size_t)br * NE + ne] + ws[OFF_QA2 + br] + ws[OFF_S1 + br * N + n];
    sc = sc > 0.f ? sc : SLOPE * sc;
    v[r] = sc;
    m = fmaxf(m, sc);
  }
  float s = 0.f;
#pragma unroll
  for (int r = 0; r < R; ++r) { v[r] = __expf(v[r] - m); s += v[r]; }
  float inv = 1.f / s;
#pragma unroll
  for (int r = 0; r < R; ++r)
    ws[OFF_SC + (size_t)(b * R + r) * NE + ne] = v[r] * inv;
}

// grid (40, 8) x 256: h_prime[br] = attn[br] @ w_original[br], then ELU.
__global__ __launch_bounds__(256) void k_hprime(const float* __restrict__ ws,
                                                float* __restrict__ out) {
  int br = blockIdx.x;
  int h = blockIdx.y * 64 + (threadIdx.x & 63);
  int ig = threadIdx.x >> 6;   // 0..3 -> rows ig*16..ig*16+15
  __shared__ __align__(16) float sAtt[64 * 64];
  const float* att = ws + OFF_SC + (size_t)br * NE;
  for (int idx = threadIdx.x; idx < 4096; idx += 256) sAtt[idx] = att[idx];
  __syncthreads();
  float acc[16] = {};
  const float* wo = ws + OFF_WO + (size_t)br * N * H;
  const float4* sAttf = reinterpret_cast<const float4*>(sAtt);
#pragma unroll 2
  for (int j4 = 0; j4 < 16; ++j4) {
    float w0 = wo[(size_t)(4 * j4 + 0) * H + h];
    float w1 = wo[(size_t)(4 * j4 + 1) * H + h];
    float w2 = wo[(size_t)(4 * j4 + 2) * H + h];
    float w3 = wo[(size_t)(4 * j4 + 3) * H + h];
#pragma unroll
    for (int ii = 0; ii < 16; ++ii) {
      float4 a4 = sAttf[(ig * 16 + ii) * 16 + j4];
      acc[ii] = fmaf(a4.x, w0, fmaf(a4.y, w1, fmaf(a4.z, w2, fmaf(a4.w, w3, acc[ii]))));
    }
  }
#pragma unroll
  for (int ii = 0; ii < 16; ++ii) {
    int i = ig * 16 + ii;
    float x = acc[ii];
    out[((size_t)br * N + i) * H + h] = x > 0.f ? x : expm1f(x);
  }
}

extern "C" void kernel_launch(void* const* d_in, const int* in_sizes, int n_in,
                              void* d_out, int out_size, void* d_ws, size_t ws_size,
                              hipStream_t stream) {
  const float* adj  = (const float*)d_in[0];
  const float* orig = (const float*)d_in[1];
  const float* ques = (const float*)d_in[2];
  const float* W    = (const float*)d_in[3];
  const float* a    = (const float*)d_in[4];
  float* out = (float*)d_out;
  float* ws  = (float*)d_ws;

  k_vecs<<<dim3(D + H), dim3(64), 0, stream>>>(W, a, ws);
  k_qproj_s1<<<dim3(BR), dim3(512), 0, stream>>>(ques, W, orig, ws);
  k_s2wo<<<dim3(WO_BLOCKS + S2_BLOCKS), dim3(256), 0, stream>>>(adj, orig, W, ws);
  k_softmax<<<dim3(B * NE / 256), dim3(256), 0, stream>>>(ws);
  k_hprime<<<dim3(BR, 8), dim3(256), 0, stream>>>(ws, out);
}

// Round 25
// 104.960 us; speedup vs baseline: 1.1007x; 1.0800x over previous
//
#include <hip/hip_runtime.h>
#include <math.h>

namespace {
constexpr int B = 4, R = 10, N = 64, E = 64, D = 300, H = 512;
constexpr int BR = B * R;        // 40
constexpr int NE = N * E;        // 4096
constexpr int S = BR * NE;       // 163840
constexpr float SLOPE = 0.2f;
constexpr int WO_BLOCKS = BR * 8;     // 320
constexpr int ATTN_BLOCKS = 1024;     // 4096 waves, 4 units each (strided)
constexpr int ATTN_WAVES = ATTN_BLOCKS * 4;   // 4096
constexpr int UPW = (B * NE) / ATTN_WAVES;    // 4

// ws layout (floats)
constexpr int OFF_V1  = 0;                 // 300   Wn @ a1
constexpr int OFF_V2  = OFF_V1 + 300;      // 300   Wn @ a2  (byte 1200, 16B-aligned)
constexpr int OFF_U1  = OFF_V2 + 300;      // 512   Wq @ a1
constexpr int OFF_U2  = OFF_U1 + H;        // 512   Wq @ a2
constexpr int OFF_QP  = OFF_U2 + H;        // 40*512 q_proj
constexpr int OFF_QA1 = OFF_QP + BR * H;   // 40
constexpr int OFF_QA2 = OFF_QA1 + BR;      // 40
constexpr int OFF_S1  = OFF_QA2 + BR;      // 2560  scores1[b,r,n] (incl. qa1)
constexpr int OFF_SC  = OFF_S1 + BR * N;   // 163840 attn (post-softmax)
constexpr int OFF_WO  = OFF_SC + S;        // 1310720 w_original
}

__device__ inline float waveReduce(float v) {
#pragma unroll
  for (int o = 32; o > 0; o >>= 1) v += __shfl_xor(v, o, 64);
  return v;
}

__device__ inline float dot4(float4 a, float4 b) {
  return a.x * b.x + a.y * b.y + a.z * b.z + a.w * b.w;
}

// grid 812 x 64: one wave per W row; dot with a1 and a2.
__global__ __launch_bounds__(64) void k_vecs(const float* __restrict__ W,
                                             const float* __restrict__ a,
                                             float* __restrict__ ws) {
  int row = blockIdx.x;
  int lane = threadIdx.x;
  const float4* rf  = reinterpret_cast<const float4*>(W + (size_t)row * H);
  const float4* a1f = reinterpret_cast<const float4*>(a);
  const float4* a2f = reinterpret_cast<const float4*>(a + H);
  float4 x0 = rf[lane], x1 = rf[64 + lane];
  float4 p0 = a1f[lane], p1 = a1f[64 + lane];
  float4 q0 = a2f[lane], q1 = a2f[64 + lane];
  float s1 = dot4(x0, p0) + dot4(x1, p1);
  float s2 = dot4(x0, q0) + dot4(x1, q1);
  s1 = waveReduce(s1);
  s2 = waveReduce(s2);
  if (lane == 0) {
    if (row < D) { ws[OFF_V1 + row] = s1; ws[OFF_V2 + row] = s2; }
    else         { ws[OFF_U1 + (row - D)] = s1; ws[OFF_U2 + (row - D)] = s2; }
  }
}

// grid 40 x 512: q_proj (4-way ILP accumulators) + qa1/qa2 + scores1 (2-row batch).
__global__ __launch_bounds__(512) void k_qproj_s1(const float* __restrict__ ques,
                                                  const float* __restrict__ W,
                                                  const float* __restrict__ orig,
                                                  float* __restrict__ ws) {
  int br = blockIdx.x, h = threadIdx.x;
  __shared__ float qs[H];
  __shared__ float red[16];
  __shared__ float qa1s;
  qs[h] = ques[(size_t)br * H + h];
  __syncthreads();
  float ac0 = 0.f, ac1 = 0.f, ac2 = 0.f, ac3 = 0.f;
#pragma unroll 4
  for (int q = 0; q < H; q += 4) {
    ac0 = fmaf(qs[q + 0], W[(size_t)(D + q + 0) * H + h], ac0);
    ac1 = fmaf(qs[q + 1], W[(size_t)(D + q + 1) * H + h], ac1);
    ac2 = fmaf(qs[q + 2], W[(size_t)(D + q + 2) * H + h], ac2);
    ac3 = fmaf(qs[q + 3], W[(size_t)(D + q + 3) * H + h], ac3);
  }
  float acc = (ac0 + ac1) + (ac2 + ac3);
  ws[OFF_QP + br * H + h] = acc;
  float p1 = qs[h] * ws[OFF_U1 + h];
  float p2 = qs[h] * ws[OFF_U2 + h];
  p1 = waveReduce(p1);
  p2 = waveReduce(p2);
  int lane = h & 63, wave = h >> 6;
  if (lane == 0) { red[wave] = p1; red[8 + wave] = p2; }
  __syncthreads();
  if (h == 0) {
    float t1 = 0.f, t2 = 0.f;
#pragma unroll
    for (int i = 0; i < 8; ++i) { t1 += red[i]; t2 += red[8 + i]; }
    ws[OFF_QA1 + br] = t1;
    ws[OFF_QA2 + br] = t2;
    qa1s = t1;
  }
  __syncthreads();
  float qa1 = qa1s;
  const float4* vf = reinterpret_cast<const float4*>(ws + OFF_V1);
  float4 va = vf[lane];
  float4 vb = (lane < 11) ? vf[64 + lane] : make_float4(0.f, 0.f, 0.f, 0.f);
  for (int n2 = wave * 8; n2 < wave * 8 + 8; n2 += 2) {
    const float4* rf0 = reinterpret_cast<const float4*>(orig + ((size_t)br * N + n2) * D);
    const float4* rf1 = reinterpret_cast<const float4*>(orig + ((size_t)br * N + n2 + 1) * D);
    float a0 = dot4(rf0[lane], va);
    float a1 = dot4(rf1[lane], va);
    if (lane < 11) {
      a0 += dot4(rf0[64 + lane], vb);
      a1 += dot4(rf1[64 + lane], vb);
    }
#pragma unroll
    for (int o = 32; o > 0; o >>= 1) {
      a0 += __shfl_xor(a0, o, 64);
      a1 += __shfl_xor(a1, o, 64);
    }
    if (lane == 0) {
      ws[OFF_S1 + br * N + n2]     = a0 + qa1;
      ws[OFF_S1 + br * N + n2 + 1] = a1 + qa1;
    }
  }
}

__device__ __forceinline__ void attn_load_x(const float* __restrict__ adj, int u,
                                            int lane, float4 (&x)[R]) {
  const float* base = adj + ((size_t)(u >> 12) * R * NE + (u & 4095)) * D;
#pragma unroll
  for (int r = 0; r < R; ++r)
    x[r] = reinterpret_cast<const float4*>(base + (size_t)r * NE * D)[lane];
}

__device__ __forceinline__ void attn_compute(const float* __restrict__ adj,
                                             float* __restrict__ ws, int u, int lane,
                                             const float4 (&x)[R],
                                             float4 va, float4 vb) {
  int b = u >> 12, ne = u & 4095, n = ne >> 6, brb = b * R;
  const float* base = adj + ((size_t)b * R * NE + ne) * D;
  bool tl = lane < 11;
  // tail loads issued first; latency hides under dots + x-reduce.
  float4 y[R];
  if (tl) {
#pragma unroll
    for (int r = 0; r < R; ++r)
      y[r] = reinterpret_cast<const float4*>(base + (size_t)r * NE * D)[64 + lane];
  }
  float add[R];
#pragma unroll
  for (int r = 0; r < R; ++r)
    add[r] = ws[OFF_QA2 + brb + r] + ws[OFF_S1 + (brb + r) * N + n];
  float acc[R];
#pragma unroll
  for (int r = 0; r < R; ++r) acc[r] = dot4(x[r], va);
  if (tl) {
#pragma unroll
    for (int r = 0; r < R; ++r) acc[r] += dot4(y[r], vb);
  }
#pragma unroll
  for (int o = 32; o > 0; o >>= 1) {
#pragma unroll
    for (int r = 0; r < R; ++r) acc[r] += __shfl_xor(acc[r], o, 64);
  }
  float m = -1e30f;
#pragma unroll
  for (int r = 0; r < R; ++r) {
    float sc = acc[r] + add[r];
    sc = sc > 0.f ? sc : SLOPE * sc;
    acc[r] = sc;
    m = fmaxf(m, sc);
  }
  float s = 0.f;
#pragma unroll
  for (int r = 0; r < R; ++r) { acc[r] = __expf(acc[r] - m); s += acc[r]; }
  float inv = 1.f / s;
  if (lane == 0) {
#pragma unroll
    for (int r = 0; r < R; ++r)
      ws[OFF_SC + (size_t)(brb + r) * NE + ne] = acc[r] * inv;
  }
}

// grid 1344 x 256, block-split (the best-measured structure, R17 = 104.6us):
//   blocks 0..319:   wo GEMM (br, h0) — independent; overlaps attn's HBM waits.
//   blocks 320..1343: persistent attn — each wave owns 4 strided units with a
//                    depth-1 software pipeline: unit i+1's 10 row-loads are in
//                    flight while unit i computes (dots/reduce/softmax/store).
__global__ __launch_bounds__(256) void k_attn_wo(const float* __restrict__ adj,
                                                 const float* __restrict__ orig,
                                                 const float* __restrict__ W,
                                                 float* __restrict__ ws) {
  __shared__ __align__(16) float sA[64 * 60];
  __shared__ __align__(16) float sB[60 * 64];
  if (blockIdx.x < WO_BLOCKS) {
    // ---- w_original tile GEMM ----
    int bi = blockIdx.x;
    int br = bi >> 3, h0 = (bi & 7) * 64;
    int t = threadIdx.x;
    const float4* sBf = reinterpret_cast<const float4*>(sB);
    int tn = t >> 4, th = t & 15;
    float acc[4][4] = {};
    for (int k0 = 0; k0 < D; k0 += 60) {
      __syncthreads();
      for (int idx = t; idx < 64 * 60; idx += 256) {
        int n = idx / 60, kk = idx % 60;
        sA[idx] = orig[((size_t)br * N + n) * D + k0 + kk];
      }
      for (int idx = t; idx < 60 * 64; idx += 256) {
        int kk = idx >> 6, hh = idx & 63;
        sB[idx] = W[(size_t)(k0 + kk) * H + h0 + hh];
      }
      __syncthreads();
#pragma unroll 4
      for (int kk = 0; kk < 60; ++kk) {
        float av[4];
#pragma unroll
        for (int i = 0; i < 4; ++i) av[i] = sA[(tn * 4 + i) * 60 + kk];
        float4 bv = sBf[kk * 16 + th];
#pragma unroll
        for (int i = 0; i < 4; ++i) {
          acc[i][0] = fmaf(av[i], bv.x, acc[i][0]);
          acc[i][1] = fmaf(av[i], bv.y, acc[i][1]);
          acc[i][2] = fmaf(av[i], bv.z, acc[i][2]);
          acc[i][3] = fmaf(av[i], bv.w, acc[i][3]);
        }
      }
    }
#pragma unroll
    for (int i = 0; i < 4; ++i) {
      int n = tn * 4 + i;
#pragma unroll
      for (int j = 0; j < 4; ++j) {
        int h = h0 + th * 4 + j;
        ws[OFF_WO + ((size_t)br * N + n) * H + h] = acc[i][j] + ws[OFF_QP + br * H + h];
      }
    }
    return;
  }
  // ---- persistent pipelined attn path ----
  int aw = (blockIdx.x - WO_BLOCKS) * 4 + (threadIdx.x >> 6);   // 0..4095
  int lane = threadIdx.x & 63;
  const float4* vf = reinterpret_cast<const float4*>(ws + OFF_V2);
  float4 va = vf[lane];
  float4 vb = (lane < 11) ? vf[64 + lane] : make_float4(0.f, 0.f, 0.f, 0.f);
  float4 xA[R], xB[R];
  attn_load_x(adj, aw, lane, xA);
#pragma unroll
  for (int i = 0; i < UPW; ++i) {
    int u = aw + i * ATTN_WAVES;
    if (i + 1 < UPW) {
      if (i & 1) attn_load_x(adj, aw + (i + 1) * ATTN_WAVES, lane, xA);
      else       attn_load_x(adj, aw + (i + 1) * ATTN_WAVES, lane, xB);
    }
    if (i & 1) attn_compute(adj, ws, u, lane, xB, va, vb);
    else       attn_compute(adj, ws, u, lane, xA, va, vb);
  }
}

// grid (40, 8) x 256: h_prime[br] = attn[br] @ w_original[br], then ELU.
__global__ __launch_bounds__(256) void k_hprime(const float* __restrict__ ws,
                                                float* __restrict__ out) {
  int br = blockIdx.x;
  int h = blockIdx.y * 64 + (threadIdx.x & 63);
  int ig = threadIdx.x >> 6;   // 0..3 -> rows ig*16..ig*16+15
  __shared__ __align__(16) float sAtt[64 * 64];
  const float* att = ws + OFF_SC + (size_t)br * NE;
  for (int idx = threadIdx.x; idx < 4096; idx += 256) sAtt[idx] = att[idx];
  __syncthreads();
  float acc[16] = {};
  const float* wo = ws + OFF_WO + (size_t)br * N * H;
  const float4* sAttf = reinterpret_cast<const float4*>(sAtt);
#pragma unroll 2
  for (int j4 = 0; j4 < 16; ++j4) {
    float w0 = wo[(size_t)(4 * j4 + 0) * H + h];
    float w1 = wo[(size_t)(4 * j4 + 1) * H + h];
    float w2 = wo[(size_t)(4 * j4 + 2) * H + h];
    float w3 = wo[(size_t)(4 * j4 + 3) * H + h];
#pragma unroll
    for (int ii = 0; ii < 16; ++ii) {
      float4 a4 = sAttf[(ig * 16 + ii) * 16 + j4];
      acc[ii] = fmaf(a4.x, w0, fmaf(a4.y, w1, fmaf(a4.z, w2, fmaf(a4.w, w3, acc[ii]))));
    }
  }
#pragma unroll
  for (int ii = 0; ii < 16; ++ii) {
    int i = ig * 16 + ii;
    float x = acc[ii];
    out[((size_t)br * N + i) * H + h] = x > 0.f ? x : expm1f(x);
  }
}

extern "C" void kernel_launch(void* const* d_in, const int* in_sizes, int n_in,
                              void* d_out, int out_size, void* d_ws, size_t ws_size,
                              hipStream_t stream) {
  const float* adj  = (const float*)d_in[0];
  const float* orig = (const float*)d_in[1];
  const float* ques = (const float*)d_in[2];
  const float* W    = (const float*)d_in[3];
  const float* a    = (const float*)d_in[4];
  float* out = (float*)d_out;
  float* ws  = (float*)d_ws;

  k_vecs<<<dim3(D + H), dim3(64), 0, stream>>>(W, a, ws);
  k_qproj_s1<<<dim3(BR), dim3(512), 0, stream>>>(ques, W, orig, ws);
  k_attn_wo<<<dim3(WO_BLOCKS + ATTN_BLOCKS), dim3(256), 0, stream>>>(adj, orig, W, ws);
  k_hprime<<<dim3(BR, 8), dim3(256), 0, stream>>>(ws, out);
}